// Round 11
// baseline (275.643 us; speedup 1.0000x reference)
//
#include <hip/hip_runtime.h>

typedef __attribute__((ext_vector_type(8))) __bf16 bf16x8;
typedef __attribute__((ext_vector_type(4))) float f32x4;
typedef __attribute__((ext_vector_type(8))) unsigned short u16x8;

__device__ __forceinline__ float bf2f(unsigned short h) {
  union { unsigned int u; float f; } a; a.u = ((unsigned int)h) << 16; return a.f;
}
// native cast -> v_cvt_pk_bf16_f32 (RNE)
__device__ __forceinline__ unsigned short f2bf(float f) {
  __bf16 h = (__bf16)f;
  unsigned short u; __builtin_memcpy(&u, &h, 2); return u;
}
__device__ __forceinline__ float fast_exp2(float x) {
#if __has_builtin(__builtin_amdgcn_exp2f)
  return __builtin_amdgcn_exp2f(x);
#else
  return exp2f(x);
#endif
}
__device__ __forceinline__ bf16x8 ld_frag(const unsigned short* p) {
  bf16x8 r; __builtin_memcpy(&r, p, 16); return r;
}
__device__ __forceinline__ void cp16(unsigned short* dst, const unsigned short* src) {
  u16x8 t; __builtin_memcpy(&t, src, 16); __builtin_memcpy(dst, &t, 16);
}

// async global->LDS 16B DMA; dest = wave-uniform base + lane*16B in all uses.
#if __has_builtin(__builtin_amdgcn_global_load_lds)
typedef __attribute__((address_space(3))) unsigned int lds_u32;
typedef const __attribute__((address_space(1))) unsigned int glb_u32;
__device__ __forceinline__ void gload16(const unsigned short* g, unsigned short* l) {
  __builtin_amdgcn_global_load_lds((glb_u32*)g, (lds_u32*)l, 16, 0, 0);
}
#else
__device__ __forceinline__ void gload16(const unsigned short* g, unsigned short* l) {
  cp16(l, g);
}
#endif

// ---------------------------------------------------------------- weight transpose (prep)
// 1024 blocks: 4 weights x 16x16 64-tiles. (cvt passes deleted: fp32->bf16 now
// happens inside the projection kernel's reg-staged A path.)
__global__ __launch_bounds__(256) void prep_kernel(
    const float* __restrict__ w0, const float* __restrict__ w1,
    const float* __restrict__ w2, const float* __restrict__ w3,
    unsigned short* __restrict__ wt)
{
  __shared__ unsigned short tile[64 * 65];
  const int t4 = blockIdx.x;
  const int t = threadIdx.x;
  const int z = t4 >> 8;
  const float* in = (z == 0) ? w0 : (z == 1) ? w1 : (z == 2) ? w2 : w3;
  unsigned short* o = wt + (size_t)z * 1048576;
  const int dim = 1024;
  const int n0 = (t4 & 15) * 64, k0 = ((t4 >> 4) & 15) * 64;
#pragma unroll
  for (int e = 0; e < 16; e++) {
    int idx = e * 256 + t;
    int i = idx >> 6, j = idx & 63;
    tile[i * 65 + j] = f2bf(in[(size_t)(k0 + i) * dim + n0 + j]);
  }
  __syncthreads();
#pragma unroll
  for (int e = 0; e < 16; e++) {
    int idx = e * 256 + t;
    int i = idx >> 6, j = idx & 63;
    o[(size_t)(n0 + i) * dim + k0 + j] = tile[j * 65 + i];
  }
}

// ---------------------------------------------------------------- merged q+k+v projections
// 2560 blocks (10/CU): [0,512) q-proj 64x64 -> qp; [512,1536) k-proj 128x64 ->
// ktiles (lane-ordered fragment tiles); [1536,2560) v-proj 128x64 -> vtiles.
// A operands read the ORIGINAL fp32 inputs, reg-staged (glb->reg->cvt->ds_write)
// -- this folds the old cvt passes into staging and kills 144 MB of intermediate
// traffic. B (bf16 transposed weights) staged via global_load_lds DMA.
// Single-barrier 3-slot pipeline; explicit vmcnt ledger: 5 events/tile for k/v
// (1 B-DMA + 4 A-dwordx4), 3 for q. vmcnt(N) drains tile kt+1, leaves kt+2 in
// flight. asm memory-clobbers pin issue windows so the count is exact.
__global__ __launch_bounds__(256, 4) void proj_kernel(
    const float* __restrict__ Qf, const float* __restrict__ Kf, const float* __restrict__ Vf,
    const unsigned short* __restrict__ WT4,
    const float* __restrict__ bq, const float* __restrict__ bk, const float* __restrict__ bv,
    unsigned short* __restrict__ qp,
    unsigned short* __restrict__ ktiles,
    unsigned short* __restrict__ vtiles)
{
  __shared__ unsigned short pool[18432];   // 36 KB: 3 slots A + 3 slots B (+Ts alias for v)
  const int bid = blockIdx.x;
  const int tid  = threadIdx.x;
  const int wave = tid >> 6;
  const int lane = tid & 63;
  const int quad = lane >> 4;
  const int l16  = lane & 15;
  const int KD = 1024, NT = 32;
  const f32x4 fz = {0.0f, 0.0f, 0.0f, 0.0f};
  const int srow0 = tid >> 2;
  const int scol  = (tid & 3) * 8;

#define Q_ISSUE(kt, X0, X1) do { \
    const int k0_ = (kt) << 5; \
    gload16(&BT[(size_t)(n0 + srow0) * KD + k0_ + scol], &pool[6144 + ((kt) % 3) * 2048 + srow0 * 32 + scol]); \
    __builtin_memcpy(&X0, &Qf[(size_t)(m0 + srow0) * KD + k0_ + scol], 16); \
    __builtin_memcpy(&X1, &Qf[(size_t)(m0 + srow0) * KD + k0_ + scol + 4], 16); \
  } while (0)
#define Q_COMMIT(slot, X0, X1) do { \
    unsigned short tu_[8]; \
    for (int j_ = 0; j_ < 4; j_++) { tu_[j_] = f2bf(X0[j_]); tu_[4 + j_] = f2bf(X1[j_]); } \
    __builtin_memcpy(&pool[(slot) * 2048 + srow0 * 32 + scol], tu_, 16); \
  } while (0)
#define Q_COMP(kt) do { \
    const unsigned short* Asb_ = pool + ((kt) % 3) * 2048; \
    const unsigned short* Bsb_ = pool + 6144 + ((kt) % 3) * 2048; \
    bf16x8 afr_[2], bfr_[2]; \
    for (int mt_ = 0; mt_ < 2; mt_++) afr_[mt_] = ld_frag(&Asb_[(wm + mt_ * 16 + l16) * 32 + quad * 8]); \
    for (int nt_ = 0; nt_ < 2; nt_++) bfr_[nt_] = ld_frag(&Bsb_[(wn + nt_ * 16 + l16) * 32 + quad * 8]); \
    for (int mt_ = 0; mt_ < 2; mt_++) \
      for (int nt_ = 0; nt_ < 2; nt_++) \
        acc[mt_][nt_] = __builtin_amdgcn_mfma_f32_16x16x32_bf16(afr_[mt_], bfr_[nt_], acc[mt_][nt_], 0, 0, 0); \
  } while (0)
#define Q_ITER(kt, I0, I1, C0, C1) do { \
    __builtin_amdgcn_s_barrier(); \
    Q_COMP(kt); \
    if ((kt) + 2 < NT) Q_ISSUE((kt) + 2, I0, I1); \
    if ((kt) + 1 < NT) { \
      if ((kt) + 2 < NT) { asm volatile("s_waitcnt vmcnt(3)" ::: "memory"); } \
      else               { asm volatile("s_waitcnt vmcnt(0)" ::: "memory"); } \
      Q_COMMIT(((kt) + 1) % 3, C0, C1); \
      asm volatile("s_waitcnt lgkmcnt(0)" ::: "memory"); \
    } \
  } while (0)

#define KV_ISSUE(AP, kt, X0, X1, X2, X3) do { \
    const int k0_ = (kt) << 5; \
    gload16(&BT[(size_t)(n0 + srow0) * KD + k0_ + scol], &pool[12288 + ((kt) % 3) * 2048 + srow0 * 32 + scol]); \
    __builtin_memcpy(&X0, &AP[(size_t)(m0 + srow0) * KD + k0_ + scol], 16); \
    __builtin_memcpy(&X1, &AP[(size_t)(m0 + srow0) * KD + k0_ + scol + 4], 16); \
    __builtin_memcpy(&X2, &AP[(size_t)(m0 + srow1) * KD + k0_ + scol], 16); \
    __builtin_memcpy(&X3, &AP[(size_t)(m0 + srow1) * KD + k0_ + scol + 4], 16); \
  } while (0)
#define KV_COMMIT(slot, X0, X1, X2, X3) do { \
    unsigned short tu_[8]; \
    for (int j_ = 0; j_ < 4; j_++) { tu_[j_] = f2bf(X0[j_]); tu_[4 + j_] = f2bf(X1[j_]); } \
    __builtin_memcpy(&pool[(slot) * 4096 + srow0 * 32 + scol], tu_, 16); \
    for (int j_ = 0; j_ < 4; j_++) { tu_[j_] = f2bf(X2[j_]); tu_[4 + j_] = f2bf(X3[j_]); } \
    __builtin_memcpy(&pool[(slot) * 4096 + srow1 * 32 + scol], tu_, 16); \
  } while (0)
#define KV_COMP(kt) do { \
    const unsigned short* Asb_ = pool + ((kt) % 3) * 4096; \
    const unsigned short* Bsb_ = pool + 12288 + ((kt) % 3) * 2048; \
    bf16x8 afr_[4], bfr_[2]; \
    for (int mt_ = 0; mt_ < 4; mt_++) afr_[mt_] = ld_frag(&Asb_[(wm + mt_ * 16 + l16) * 32 + quad * 8]); \
    for (int nt_ = 0; nt_ < 2; nt_++) bfr_[nt_] = ld_frag(&Bsb_[(wn + nt_ * 16 + l16) * 32 + quad * 8]); \
    for (int mt_ = 0; mt_ < 4; mt_++) \
      for (int nt_ = 0; nt_ < 2; nt_++) \
        acc[mt_][nt_] = __builtin_amdgcn_mfma_f32_16x16x32_bf16(afr_[mt_], bfr_[nt_], acc[mt_][nt_], 0, 0, 0); \
  } while (0)
#define KV_ITER(AP, kt, I0, I1, I2, I3, C0, C1, C2, C3) do { \
    __builtin_amdgcn_s_barrier(); \
    KV_COMP(kt); \
    if ((kt) + 2 < NT) KV_ISSUE(AP, (kt) + 2, I0, I1, I2, I3); \
    if ((kt) + 1 < NT) { \
      if ((kt) + 2 < NT) { asm volatile("s_waitcnt vmcnt(5)" ::: "memory"); } \
      else               { asm volatile("s_waitcnt vmcnt(0)" ::: "memory"); } \
      KV_COMMIT(((kt) + 1) % 3, C0, C1, C2, C3); \
      asm volatile("s_waitcnt lgkmcnt(0)" ::: "memory"); \
    } \
  } while (0)

  if (bid < 512) {
    // ---------------- q-proj: 64x64 tile ----------------
    const int m0 = (bid & 31) * 64;
    const int n0 = (bid >> 5) * 64;
    const int wm = (wave & 1) * 32;
    const int wn = (wave >> 1) * 32;
    const unsigned short* BT = WT4;
    f32x4 acc[2][2];
    for (int i = 0; i < 2; i++)
      for (int j = 0; j < 2; j++) acc[i][j] = fz;
    f32x4 qa0, qa1, qb0, qb1;
    Q_ISSUE(0, qa0, qa1);
    Q_ISSUE(1, qb0, qb1);
    asm volatile("s_waitcnt vmcnt(3)" ::: "memory");
    Q_COMMIT(0, qa0, qa1);
    asm volatile("s_waitcnt lgkmcnt(0)" ::: "memory");
    for (int kt = 0; kt < NT; kt += 2) {
      Q_ITER(kt,     qa0, qa1, qb0, qb1);
      Q_ITER(kt + 1, qb0, qb1, qa0, qa1);
    }
    const float cscale = 0.18033688011112042f;   // 0.125 * log2(e)
    for (int nt = 0; nt < 2; nt++) {
      int col = n0 + wn + nt * 16 + l16;
      float bsc = bq[col];
      for (int mt = 0; mt < 2; mt++) {
        int rowb = m0 + wm + mt * 16 + quad * 4;
        for (int r = 0; r < 4; r++)
          qp[(size_t)(rowb + r) * 1024 + col] = f2bf((acc[mt][nt][r] + bsc) * cscale);
      }
    }
  } else if (bid < 1536) {
    // ---------------- k-proj: 128x64 tile -> fragment tiles ----------------
    const int tb = bid - 512;
    const int m0 = (tb & 63) * 128;
    const int n0 = (tb >> 6) * 64;
    const int wm = (wave & 1) * 64;
    const int wn = (wave >> 1) * 32;
    const int srow1 = srow0 + 64;
    const unsigned short* BT = WT4 + 1048576;
    f32x4 acc[4][2];
    for (int i = 0; i < 4; i++)
      for (int j = 0; j < 2; j++) acc[i][j] = fz;
    f32x4 ka0, ka1, ka2, ka3, kb0, kb1, kb2, kb3;
    KV_ISSUE(Kf, 0, ka0, ka1, ka2, ka3);
    KV_ISSUE(Kf, 1, kb0, kb1, kb2, kb3);
    asm volatile("s_waitcnt vmcnt(5)" ::: "memory");
    KV_COMMIT(0, ka0, ka1, ka2, ka3);
    asm volatile("s_waitcnt lgkmcnt(0)" ::: "memory");
    for (int kt = 0; kt < NT; kt += 2) {
      KV_ITER(Kf, kt,     ka0, ka1, ka2, ka3, kb0, kb1, kb2, kb3);
      KV_ITER(Kf, kt + 1, kb0, kb1, kb2, kb3, ka0, ka1, ka2, ka3);
    }
    for (int nt = 0; nt < 2; nt++) {
      const int col = n0 + wn + nt * 16 + l16;
      const float bvv = bk[col];
      const int h  = col >> 6;
      const int dk = col & 63;
      const int kc = dk >> 5;
      const int dq = (dk >> 3) & 3;
      const int de = dk & 7;
      for (int mt = 0; mt < 4; mt++) {
        for (int r = 0; r < 4; r++) {
          const int row = m0 + wm + mt * 16 + quad * 4 + r;
          const int bb = row >> 11, key = row & 2047;
          const size_t tile = ((size_t)((bb * 16 + h) * 32 + (key >> 6))) * 4096;
          const int knt = (key & 63) >> 4;
          const int kl16 = key & 15;
          ktiles[tile + ((size_t)((knt * 2 + kc) * 64 + dq * 16 + kl16)) * 8 + de] =
              f2bf(acc[mt][nt][r] + bvv);
        }
      }
    }
  } else {
    // ---------------- v-proj: 128x64 tile -> fragment tiles (Ts transpose) ----------------
    const int tb = bid - 1536;
    const int m0 = (tb & 63) * 128;
    const int n0 = (tb >> 6) * 64;
    const int wm = (wave & 1) * 64;
    const int wn = (wave >> 1) * 32;
    const int srow1 = srow0 + 64;
    const unsigned short* BT = WT4 + 2097152;
    f32x4 acc[4][2];
    for (int i = 0; i < 4; i++)
      for (int j = 0; j < 2; j++) acc[i][j] = fz;
    f32x4 va0, va1, va2, va3, vb0, vb1, vb2, vb3;
    KV_ISSUE(Vf, 0, va0, va1, va2, va3);
    KV_ISSUE(Vf, 1, vb0, vb1, vb2, vb3);
    asm volatile("s_waitcnt vmcnt(5)" ::: "memory");
    KV_COMMIT(0, va0, va1, va2, va3);
    asm volatile("s_waitcnt lgkmcnt(0)" ::: "memory");
    for (int kt = 0; kt < NT; kt += 2) {
      KV_ITER(Vf, kt,     va0, va1, va2, va3, vb0, vb1, vb2, vb3);
      KV_ITER(Vf, kt + 1, vb0, vb1, vb2, vb3, va0, va1, va2, va3);
    }
    __syncthreads();   // all waves done with pool before Ts aliases it

    unsigned short* Ts = pool + wave * 2304;
    for (int nt = 0; nt < 2; nt++) {
      const float bvv = bv[n0 + wn + nt * 16 + l16];
      for (int mt = 0; mt < 4; mt++)
        for (int r = 0; r < 4; r++)
          Ts[(nt * 16 + l16) * 72 + mt * 16 + quad * 4 + r] = f2bf(acc[mt][nt][r] + bvv);
    }
    {
      const int R0 = m0 + wm;                 // 64-aligned
      const int b  = R0 >> 11;
      const int ktile = (R0 & 2047) >> 6;
      const int h = n0 >> 6;
      const int dv_local = lane >> 1;         // 0..31
      const int kc = lane & 1;
      const int dv = wn + dv_local;           // 0..63
      const int dvt = dv >> 4, vl16 = dv & 15;
      const size_t vtile = ((size_t)((b * 16 + h) * 32 + ktile)) * 4096;
      for (int jb = 0; jb < 4; jb++) {
        const size_t dst = vtile + ((size_t)((dvt * 2 + kc) * 64 + jb * 16 + vl16)) * 8;
        cp16((unsigned short*)&vtiles[dst], &Ts[dv_local * 72 + kc * 32 + jb * 8]);
      }
    }
  }
#undef Q_ISSUE
#undef Q_COMMIT
#undef Q_COMP
#undef Q_ITER
#undef KV_ISSUE
#undef KV_COMMIT
#undef KV_COMP
#undef KV_ITER
}

// ---------------------------------------------------------------- GEMM (B^T), 64x64 tile
// out-proj (M=2048): grid (32,16)=512 blocks -> 2 blocks/CU. Single-barrier
// 3-buffer pipeline (A is bf16 attn output -> keeps gload16 DMA staging).
__global__ __launch_bounds__(256) void gemm_bt64_kernel(
    const unsigned short* __restrict__ A,
    const unsigned short* __restrict__ BT,
    const float* __restrict__ bias,
    unsigned short* __restrict__ C,
    int M, int N, int K, float cscale)
{
  __shared__ unsigned short pool[12288];   // As=pool+s*2048, Bs=pool+6144+s*2048
  const int tid  = threadIdx.x;
  const int wave = tid >> 6;
  const int lane = tid & 63;
  const int quad = lane >> 4;
  const int l16  = lane & 15;
  const int m0 = blockIdx.x * 64;
  const int n0 = blockIdx.y * 64;
  const int wm = (wave & 1) * 32;
  const int wn = (wave >> 1) * 32;

  const f32x4 fz = {0.0f, 0.0f, 0.0f, 0.0f};
  f32x4 acc[2][2];
#pragma unroll
  for (int i = 0; i < 2; i++)
#pragma unroll
    for (int j = 0; j < 2; j++) acc[i][j] = fz;

  const int srow0 = tid >> 2;
  const int scol  = (tid & 3) * 8;
  const int gcol  = ((tid & 3) ^ ((tid >> 2) & 3)) * 8;
  const int sq    = (quad ^ (l16 & 3)) * 8;

  auto stage = [&](int s, int k0) {
    unsigned short* Asb = pool + s * 2048;
    unsigned short* Bsb = pool + 6144 + s * 2048;
    gload16(&A[(size_t)(m0 + srow0) * K + k0 + gcol], &Asb[srow0 * 32 + scol]);
    gload16(&BT[(size_t)(n0 + srow0) * K + k0 + gcol], &Bsb[srow0 * 32 + scol]);
  };

  const int NT = K >> 5;
  stage(0, 0);
  stage(1, 32);
  for (int kt = 0; kt < NT; ++kt) {
    if (kt + 1 < NT) asm volatile("s_waitcnt vmcnt(2)" ::: "memory");
    else             asm volatile("s_waitcnt vmcnt(0)" ::: "memory");
    __builtin_amdgcn_s_barrier();
    const int cur = kt % 3;
    const unsigned short* Asb = pool + cur * 2048;
    const unsigned short* Bsb = pool + 6144 + cur * 2048;
    bf16x8 afr[2], bfr[2];
#pragma unroll
    for (int mt = 0; mt < 2; mt++) afr[mt] = ld_frag(&Asb[(wm + mt * 16 + l16) * 32 + sq]);
#pragma unroll
    for (int nt = 0; nt < 2; nt++) bfr[nt] = ld_frag(&Bsb[(wn + nt * 16 + l16) * 32 + sq]);
#pragma unroll
    for (int mt = 0; mt < 2; mt++)
#pragma unroll
      for (int nt = 0; nt < 2; nt++)
        acc[mt][nt] = __builtin_amdgcn_mfma_f32_16x16x32_bf16(afr[mt], bfr[nt], acc[mt][nt], 0, 0, 0);
    if (kt + 2 < NT) stage((kt + 2) % 3, (kt + 2) << 5);
  }

#pragma unroll
  for (int nt = 0; nt < 2; nt++) {
    int col = n0 + wn + nt * 16 + l16;
    float bsc = bias[col];
#pragma unroll
    for (int mt = 0; mt < 2; mt++) {
      int rowb = m0 + wm + mt * 16 + quad * 4;
#pragma unroll
      for (int r = 0; r < 4; r++)
        C[(size_t)(rowb + r) * N + col] = f2bf((acc[mt][nt][r] + bsc) * cscale);
    }
  }
}

// ---------------------------------------------------------------- attention
// 8-wave (512-thread) shared-tile flash attention. Block = (bh, 128 q-rows);
// all waves march the 32 K/V tiles together; each 8KB K/V tile DMA'd once into
// TRIPLE-buffered LDS (single barrier per tile, 2 tiles in flight). Lane-ordered
// fragment layout: conflict-free LDS reads. Fixed-max softmax in log2 domain.
__global__ __launch_bounds__(512) void attn_kernel(
    const unsigned short* __restrict__ qp,   // [B*512, 1024] bf16, pre-scaled
    const unsigned short* __restrict__ kp,   // lane-ordered tiles [bh][32][4096]
    const unsigned short* __restrict__ vt,   // lane-ordered tiles [bh][32][4096]
    const int* __restrict__ mask,            // [B, 2048]
    unsigned short* __restrict__ attn)       // [B*512, 1024] bf16
{
  __shared__ unsigned short Kb[3][4096];
  __shared__ unsigned short Vb[3][4096];
  __shared__ int Ms[2048];
  __shared__ unsigned short Ps[8][16 * 72];

  const int tid  = threadIdx.x;
  const int wave = tid >> 6;
  const int lane = tid & 63;
  const int quad = lane >> 4;
  const int l16  = lane & 15;
  const int bid  = blockIdx.x;
  const int bh = bid & 63;       // XCD = bid%8 = bh%8
  const int qg = bid >> 6;       // q-group 0..3 (128 rows each)
  const int b = bh >> 4, h = bh & 15;

  bf16x8 aq[2];
  {
    const size_t qbase = ((size_t)(b * 512 + qg * 128 + wave * 16 + l16)) * 1024 + h * 64;
#pragma unroll
    for (int kc = 0; kc < 2; kc++)
      aq[kc] = ld_frag(&qp[qbase + kc * 32 + quad * 8]);
  }
  {
    const unsigned short* mg = (const unsigned short*)(mask + b * 2048);
    unsigned short* ml = (unsigned short*)Ms;
    gload16(mg + tid * 8, ml + tid * 8);
  }
  asm volatile("s_waitcnt vmcnt(0)" ::: "memory");

  const size_t kvbase = (size_t)bh * 131072;
  auto stageKV = [&](int s, int kt) {
    const unsigned short* ksrc = kp + kvbase + (size_t)kt * 4096;
    const unsigned short* vsrc = vt + kvbase + (size_t)kt * 4096;
    gload16(ksrc + tid * 8, &Kb[s][tid * 8]);
    gload16(vsrc + tid * 8, &Vb[s][tid * 8]);
  };

  const f32x4 fz = {0.0f, 0.0f, 0.0f, 0.0f};
  float l_i[4];
  f32x4 O[4];
#pragma unroll
  for (int r = 0; r < 4; r++) { l_i[r] = 0.0f; O[r] = fz; }

  stageKV(0, 0);
  stageKV(1, 1);
  for (int kt = 0; kt < 32; ++kt) {
    if (kt + 1 < 32) asm volatile("s_waitcnt vmcnt(2)" ::: "memory");
    else             asm volatile("s_waitcnt vmcnt(0)" ::: "memory");
    __builtin_amdgcn_s_barrier();
    const int cur = kt % 3;

    int mk[4];
#pragma unroll
    for (int nt = 0; nt < 4; nt++) mk[nt] = Ms[kt * 64 + nt * 16 + l16];

    f32x4 s[4];
#pragma unroll
    for (int nt = 0; nt < 4; nt++) s[nt] = fz;
    __builtin_amdgcn_s_setprio(1);
#pragma unroll
    for (int nt = 0; nt < 4; nt++)
#pragma unroll
      for (int kc = 0; kc < 2; kc++) {
        bf16x8 bk = ld_frag(&Kb[cur][(nt * 2 + kc) * 512 + lane * 8]);
        s[nt] = __builtin_amdgcn_mfma_f32_16x16x32_bf16(aq[kc], bk, s[nt], 0, 0, 0);
      }
    __builtin_amdgcn_s_setprio(0);

#pragma unroll
    for (int nt = 0; nt < 4; nt++) {
      bool ok = (mk[nt] != 0);
#pragma unroll
      for (int r = 0; r < 4; r++) {
        float p = ok ? fast_exp2(s[nt][r]) : 0.0f;
        l_i[r] += p;
        Ps[wave][(quad * 4 + r) * 72 + nt * 16 + l16] = f2bf(p);
      }
    }

    bf16x8 ap[2];
#pragma unroll
    for (int kc = 0; kc < 2; kc++)
      ap[kc] = ld_frag(&Ps[wave][l16 * 72 + kc * 32 + quad * 8]);
    __builtin_amdgcn_s_setprio(1);
#pragma unroll
    for (int dvt = 0; dvt < 4; dvt++)
#pragma unroll
      for (int kc = 0; kc < 2; kc++) {
        bf16x8 bvf = ld_frag(&Vb[cur][(dvt * 2 + kc) * 512 + lane * 8]);
        O[dvt] = __builtin_amdgcn_mfma_f32_16x16x32_bf16(ap[kc], bvf, O[dvt], 0, 0, 0);
      }
    __builtin_amdgcn_s_setprio(0);
    if (kt + 2 < 32) stageKV((kt + 2) % 3, kt + 2);
  }

#pragma unroll
  for (int off = 1; off < 16; off <<= 1)
#pragma unroll
    for (int r = 0; r < 4; r++) l_i[r] += __shfl_xor(l_i[r], off);

  const int growb = b * 512 + qg * 128 + wave * 16 + quad * 4;
#pragma unroll
  for (int r = 0; r < 4; r++) {
    const float inv = (l_i[r] > 0.0f) ? (1.0f / l_i[r]) : 0.0f;
#pragma unroll
    for (int dvt = 0; dvt < 4; dvt++)
      attn[(size_t)(growb + r) * 1024 + h * 64 + dvt * 16 + l16] = f2bf(O[dvt][r] * inv);
  }
}

// ---------------------------------------------------------------- layernorm
__global__ __launch_bounds__(256) void ln_kernel(
    const unsigned short* __restrict__ x,
    const float* __restrict__ resid,
    const float* __restrict__ gamma,
    const float* __restrict__ beta,
    float* __restrict__ out)
{
  const int row = blockIdx.x;
  const int t = threadIdx.x;
  const int wave = t >> 6, lane = t & 63;
  __shared__ float red[8];
  float v[4];
  float s1 = 0.0f, s2 = 0.0f;
#pragma unroll
  for (int i = 0; i < 4; i++) {
    int e = t + i * 256;
    float val = bf2f(x[(size_t)row * 1024 + e]) + resid[(size_t)row * 1024 + e];
    v[i] = val; s1 += val; s2 += val * val;
  }
#pragma unroll
  for (int off = 1; off < 64; off <<= 1) { s1 += __shfl_xor(s1, off); s2 += __shfl_xor(s2, off); }
  if (lane == 0) { red[wave] = s1; red[4 + wave] = s2; }
  __syncthreads();
  s1 = red[0] + red[1] + red[2] + red[3];
  s2 = red[4] + red[5] + red[6] + red[7];
  float mu  = s1 * (1.0f / 1024.0f);
  float var = s2 * (1.0f / 1024.0f) - mu * mu;
  float rstd = rsqrtf(var + 1e-5f);
#pragma unroll
  for (int i = 0; i < 4; i++) {
    int e = t + i * 256;
    out[(size_t)row * 1024 + e] = (v[i] - mu) * rstd * gamma[e] + beta[e];
  }
}

// ---------------------------------------------------------------- launch
extern "C" void kernel_launch(void* const* d_in, const int* in_sizes, int n_in,
                              void* d_out, int out_size, void* d_ws, size_t ws_size,
                              hipStream_t stream) {
  (void)out_size; (void)ws_size;
  const float* Q = (const float*)d_in[0];
  const float* K = (const float*)d_in[1];
  const float* V = (const float*)d_in[2];

  int ix = 3;
  if (ix < n_in && in_sizes[ix] == 1) ix++;   // skip node_num scalar if passed
  const int* mask  = (const int*)d_in[ix++];
  const float* Wq = (const float*)d_in[ix++]; const float* bq = (const float*)d_in[ix++];
  const float* Wk = (const float*)d_in[ix++]; const float* bk = (const float*)d_in[ix++];
  const float* Wv = (const float*)d_in[ix++]; const float* bv = (const float*)d_in[ix++];
  const float* Wo = (const float*)d_in[ix++]; const float* bo = (const float*)d_in[ix++];
  const float* gm = (const float*)d_in[ix++]; const float* bt = (const float*)d_in[ix++];

  char* ws = (char*)d_ws;
  dim3 blk(256);
  dim3 blk512(512);

  // ws layout (48 MB of 64, no aliasing needed):
  //  @0  WT4 (8 MB) | @8 qp (4) | @12 ktiles (16) | @28 vtiles (16) | @44 at (4)
  unsigned short* WT4    = (unsigned short*)(ws);
  unsigned short* qp     = (unsigned short*)(ws + (8ull  << 20));
  unsigned short* ktiles = (unsigned short*)(ws + (12ull << 20));
  unsigned short* vtiles = (unsigned short*)(ws + (28ull << 20));
  unsigned short* at     = (unsigned short*)(ws + (44ull << 20));

  prep_kernel<<<dim3(1024), blk, 0, stream>>>(Wq, Wk, Wv, Wo, WT4);
  proj_kernel<<<dim3(2560), blk, 0, stream>>>(Q, K, V, WT4, bq, bk, bv, qp, ktiles, vtiles);
  attn_kernel<<<dim3(256), blk512, 0, stream>>>(qp, ktiles, vtiles, mask, at);
  gemm_bt64_kernel<<<dim3(32, 16), blk, 0, stream>>>(at, WT4 + 3145728, bo, qp, 2048, 1024, 1024, 1.0f);
  ln_kernel<<<dim3(2048), blk, 0, stream>>>(qp, Q, gm, bt, (float*)d_out);
}